// Round 6
// baseline (1396.112 us; speedup 1.0000x reference)
//
#include <hip/hip_runtime.h>
#include <hip/hip_bf16.h>

#define NPTS    4096
#define NBATCH  16
#define NPOINT  1024
#define NSAMPLE 32

// ---------------- DPP helpers (wave reductions without LDS round-trips) ---
#define ROW_SHR1  0x111
#define ROW_SHR2  0x112
#define ROW_SHR4  0x114
#define ROW_SHR8  0x118
#define ROW_BC15  0x142
#define ROW_BC31  0x143

template<int CTRL>
__device__ __forceinline__ unsigned dpp_mov(unsigned v) {
    // bound_ctrl=true: invalid source lanes produce 0 (safe: all values >= 0)
    return (unsigned)__builtin_amdgcn_update_dpp(0, (int)v, CTRL, 0xF, 0xF, true);
}
template<int CTRL>
__device__ __forceinline__ float dpp_maxf(float v) {
    unsigned t = dpp_mov<CTRL>(__float_as_uint(v));
    return fmaxf(v, __uint_as_float(t));
}
__device__ __forceinline__ float readlane_f(float v, int lane) {
    return __uint_as_float(
        (unsigned)__builtin_amdgcn_readlane((int)__float_as_uint(v), lane));
}

// ---------------- K1: farthest point sampling --------------------------------
// One block per batch, 1024 threads (16 waves, 4/SIMD), 4 CONTIGUOUS points
// per thread. R2-R5 lesson: the compiler refuses to keep 64-element per-thread
// arrays in arch VGPRs (AGPR shuttling, ~2x slowdown; launch_bounds(,1) didn't
// change it). 4 pts/thread needs only ~40 VGPRs -> genuinely register-resident,
// and 4 waves/SIMD hide both dist-loop latency and each other's serial reduce
// tails. Candidate COORDS tracked via cndmask; per-wave winner publishes
// {val,x,y,z} float4 to one of 16 slots; cross-wave reduce = ds_read_b128 of
// slot[lane&15] + 4-step DPP row-max + ballot + 3 readlanes -> SGPR centroid.
// Outputs accumulate in a 16 KB LDS plane, one coalesced dump at the end --
// no global ops inside the loop. Exact f32 (no fma) distances; tie-breaks
// replicate np argmax (first max): strict > within thread (ascending j),
// lowest lane via ctz(ballot) (ascending contiguous ranges), lowest slot
// (= lowest wave) across waves.
__global__ __launch_bounds__(1024, 1) void fps_kernel(
    const float* __restrict__ xyz, float* __restrict__ newxyz)
{
    const int b    = blockIdx.x;
    const int tid  = threadIdx.x;
    const int lane = tid & 63;
    const int w    = tid >> 6;                       // 16 waves
    const float* xb = xyz + (size_t)b * 3 * NPTS;

    __shared__ float4 slots[2][16];
    __shared__ float4 NOUT[NPOINT];                  // 16 KiB output staging

    float px[4], py[4], pz[4], dist[4];
    {
        const int n4 = tid * 4;
        float4 xs = *(const float4*)(xb + n4);
        float4 ys = *(const float4*)(xb + NPTS + n4);
        float4 zs = *(const float4*)(xb + 2*NPTS + n4);
        px[0] = xs.x; px[1] = xs.y; px[2] = xs.z; px[3] = xs.w;
        py[0] = ys.x; py[1] = ys.y; py[2] = ys.z; py[3] = ys.w;
        pz[0] = zs.x; pz[1] = zs.y; pz[2] = zs.z; pz[3] = zs.w;
    }
    #pragma unroll
    for (int j = 0; j < 4; ++j) dist[j] = 1e10f;

    // first centroid = point 0 (uniform address -> scalar loads)
    float cx = xb[0], cy = xb[NPTS], cz = xb[2*NPTS];
    if (tid == 0) NOUT[0] = make_float4(cx, cy, cz, 0.f);

    for (int i = 1; i < NPOINT; ++i) {
        float bv = -1.0f, bx = 0.f, by = 0.f, bz = 0.f;
        #pragma unroll
        for (int j = 0; j < 4; ++j) {
            float dx = px[j] - cx;
            float dy = py[j] - cy;
            float dz = pz[j] - cz;
            // exact f32, no contraction, same assoc as np: (dx*dx+dy*dy)+dz*dz
            float d = __fadd_rn(__fadd_rn(__fmul_rn(dx,dx), __fmul_rn(dy,dy)),
                                __fmul_rn(dz,dz));
            float nd = fminf(dist[j], d);
            dist[j] = nd;
            bool t = nd > bv;                        // strict > : first max wins
            bv = t ? nd    : bv;
            bx = t ? px[j] : bx;
            by = t ? py[j] : by;
            bz = t ? pz[j] : bz;
        }

        // intra-wave: max value, then first (lowest-lane) holder's coords
        float wv = bv;
        wv = dpp_maxf<ROW_SHR1>(wv);
        wv = dpp_maxf<ROW_SHR2>(wv);
        wv = dpp_maxf<ROW_SHR4>(wv);
        wv = dpp_maxf<ROW_SHR8>(wv);
        wv = dpp_maxf<ROW_BC15>(wv);
        wv = dpp_maxf<ROW_BC31>(wv);                 // lane 63 = wave max
        float wmax = readlane_f(wv, 63);
        unsigned long long mask = __ballot(bv == wmax);
        int L = (int)__builtin_ctzll(mask);          // lowest lane = lowest index
        float sx = readlane_f(bx, L);
        float sy = readlane_f(by, L);
        float sz = readlane_f(bz, L);
        if (lane == 0)
            slots[i & 1][w] = make_float4(wmax, sx, sy, sz);
        __syncthreads();

        // cross-wave: b128 read of slot[lane&15], 4-step DPP row-max (a row is
        // 16 lanes, SHR stays in-row so lane 15 = max of slots 0..15), ballot,
        // first holder -> SGPR centroid.
        float4 s = slots[i & 1][lane & 15];
        float v = s.x;
        v = dpp_maxf<ROW_SHR1>(v);
        v = dpp_maxf<ROW_SHR2>(v);
        v = dpp_maxf<ROW_SHR4>(v);
        v = dpp_maxf<ROW_SHR8>(v);                   // lane 15 = max of slots 0..15
        float gmax = readlane_f(v, 15);
        unsigned long long m2 = __ballot(s.x == gmax);
        int W = (int)__builtin_ctzll(m2);            // lowest lane = lowest slot
        cx = readlane_f(s.y, W);                     // SGPR centroid
        cy = readlane_f(s.z, W);
        cz = readlane_f(s.w, W);
        if (tid == 0) NOUT[i] = make_float4(cx, cy, cz, 0.f);
    }

    __syncthreads();
    {
        const int t = tid;
        float4 c = NOUT[t];
        newxyz[b*3*NPOINT + t]            = c.x;
        newxyz[b*3*NPOINT + NPOINT + t]   = c.y;
        newxyz[b*3*NPOINT + 2*NPOINT + t] = c.z;
    }
}

// ---------------- K2: query_ball_point ---------------------------------------
// One wave per centroid: ordered scan of all 4096 points; ballot + prefix
// popcount emits the first 32 in-radius indices in ascending order; pad with
// the first found index. Exact f32 distances (no fma).
__global__ __launch_bounds__(256) void ball_kernel(
    const float* __restrict__ xyz, const float* __restrict__ newxyz,
    int* __restrict__ ball_idx)
{
    const int gid  = blockIdx.x * 256 + threadIdx.x;
    const int wid  = gid >> 6;                 // 0 .. 16383
    const int lane = threadIdx.x & 63;
    const int b    = wid >> 10;
    const int m    = wid & (NPOINT - 1);
    const float r2 = (float)(0.2 * 0.2);

    const float* xb = xyz + (size_t)b * 3 * NPTS;
    const float cx = newxyz[b*3*NPOINT + m];
    const float cy = newxyz[b*3*NPOINT + NPOINT + m];
    const float cz = newxyz[b*3*NPOINT + 2*NPOINT + m];
    int* out = ball_idx + (size_t)wid * NSAMPLE;

    int base = 0, first = 0;
    for (int c0 = 0; c0 < NPTS; c0 += 64) {
        const int n = c0 + lane;
        float dx = xb[n] - cx, dy = xb[NPTS+n] - cy, dz = xb[2*NPTS+n] - cz;
        float d = __fadd_rn(__fadd_rn(__fmul_rn(dx,dx), __fmul_rn(dy,dy)),
                            __fmul_rn(dz,dz));
        bool inb = (d <= r2);
        unsigned long long mask = __ballot(inb);
        if (base == 0 && mask != 0ull) first = c0 + (int)__builtin_ctzll(mask);
        int pos = base + __popcll(mask & ((1ull << lane) - 1ull));
        if (inb && pos < NSAMPLE) out[pos] = n;
        base += __popcll(mask);
        if (base >= NSAMPLE) break;
    }
    if (lane < NSAMPLE && lane >= base) out[lane] = first;  // pad with first index
}

// ---------------- K0: weight prep --------------------------------------------
// Transpose w0,w1 to k-major (so the MLP's per-k weight reads are contiguous
// wave-uniform scalar loads) and fold conv-bias + batchnorm into scale/shift.
__global__ __launch_bounds__(256) void setup_kernel(
    const float* __restrict__ w0, const float* __restrict__ b0,
    const float* __restrict__ g0, const float* __restrict__ be0,
    const float* __restrict__ m0, const float* __restrict__ v0,
    const float* __restrict__ w1, const float* __restrict__ b1,
    const float* __restrict__ g1, const float* __restrict__ be1,
    const float* __restrict__ m1, const float* __restrict__ v1,
    const float* __restrict__ b2, const float* __restrict__ g2,
    const float* __restrict__ be2, const float* __restrict__ m2,
    const float* __restrict__ v2, float* __restrict__ wp)
{
    const int t = threadIdx.x;
    for (int i = t; i < 64*67; i += 256) {
        int o = i / 67, k = i - o*67;
        wp[k*64 + o] = w0[i];                       // w0t [67][64]
    }
    for (int i = t; i < 64*64; i += 256) {
        int o = i >> 6, k = i & 63;
        wp[4288 + k*64 + o] = w1[i];                // w1t [64][64]
    }
    if (t < 64) {
        float s0 = g0[t] / sqrtf(v0[t] + 1e-5f);
        wp[8384 + t] = s0;
        wp[8448 + t] = (b0[t] - m0[t]) * s0 + be0[t];
        float s1 = g1[t] / sqrtf(v1[t] + 1e-5f);
        wp[8512 + t] = s1;
        wp[8576 + t] = (b1[t] - m1[t]) * s1 + be1[t];
    }
    if (t < 128) {
        float s2 = g2[t] / sqrtf(v2[t] + 1e-5f);
        wp[8640 + t] = s2;
        wp[8768 + t] = (b2[t] - m2[t]) * s2 + be2[t];
    }
}

// ---------------- K3: gather + 3-layer MLP + maxpool -------------------------
// One lane per (centroid, sample) column. 64 lanes = 2 centroids x 32 samples.
// All activations in VGPRs; weights via wave-uniform scalar loads; max over
// 32 samples with a 5-step DPP chain; lanes 31/63 store.
__global__ __launch_bounds__(256) void mlp_kernel(
    const float* __restrict__ xyz, const float* __restrict__ points,
    const float* __restrict__ newxyz, const int* __restrict__ ball_idx,
    const float* __restrict__ wp, const float* __restrict__ w2,
    float* __restrict__ out)
{
    const int col = blockIdx.x * 256 + threadIdx.x;   // 0 .. 524287
    const int m   = (col >> 5) & (NPOINT - 1);
    const int b   = col >> 15;
    const int p   = ball_idx[col];

    const float* xb = xyz + (size_t)b * 3 * NPTS;
    float in[67];
    in[0] = xb[p]          - newxyz[b*3*NPOINT + m];
    in[1] = xb[NPTS + p]   - newxyz[b*3*NPOINT + NPOINT + m];
    in[2] = xb[2*NPTS + p] - newxyz[b*3*NPOINT + 2*NPOINT + m];
    const float* pb = points + (size_t)b * 64 * NPTS;
    #pragma unroll
    for (int c = 0; c < 64; ++c) in[3 + c] = pb[c * NPTS + p];

    const float* w0t = wp;
    const float* w1t = wp + 4288;
    const float* sc0 = wp + 8384;
    const float* sh0 = wp + 8448;
    const float* sc1 = wp + 8512;
    const float* sh1 = wp + 8576;
    const float* sc2 = wp + 8640;
    const float* sh2 = wp + 8768;

    float h[64];
    #pragma unroll
    for (int o = 0; o < 64; ++o) h[o] = 0.0f;
    #pragma unroll
    for (int k = 0; k < 67; ++k) {
        const float x = in[k];
        #pragma unroll
        for (int o = 0; o < 64; ++o) h[o] = fmaf(w0t[k*64 + o], x, h[o]);
    }
    #pragma unroll
    for (int o = 0; o < 64; ++o)
        h[o] = fmaxf(fmaf(h[o], sc0[o], sh0[o]), 0.0f);

    float g[64];
    #pragma unroll
    for (int o = 0; o < 64; ++o) g[o] = 0.0f;
    #pragma unroll
    for (int k = 0; k < 64; ++k) {
        const float x = h[k];
        #pragma unroll
        for (int o = 0; o < 64; ++o) g[o] = fmaf(w1t[k*64 + o], x, g[o]);
    }
    #pragma unroll
    for (int o = 0; o < 64; ++o)
        g[o] = fmaxf(fmaf(g[o], sc1[o], sh1[o]), 0.0f);

    float* outb = out + (size_t)b * 128 * NPOINT + m;
    #pragma unroll 2
    for (int o = 0; o < 128; ++o) {
        float acc = 0.0f;
        const float* wr = w2 + o * 64;
        #pragma unroll
        for (int k = 0; k < 64; ++k) acc = fmaf(wr[k], g[k], acc);
        acc = fmaxf(fmaf(acc, sc2[o], sh2[o]), 0.0f);
        acc = dpp_maxf<ROW_SHR1>(acc);
        acc = dpp_maxf<ROW_SHR2>(acc);
        acc = dpp_maxf<ROW_SHR4>(acc);
        acc = dpp_maxf<ROW_SHR8>(acc);
        acc = dpp_maxf<ROW_BC15>(acc);            // lane31 = max(0..31), lane63 = max(32..63)
        if ((threadIdx.x & 31) == 31) outb[o * NPOINT] = acc;
    }
}

// ---------------- launch ------------------------------------------------------
extern "C" void kernel_launch(void* const* d_in, const int* in_sizes, int n_in,
                              void* d_out, int out_size, void* d_ws, size_t ws_size,
                              hipStream_t stream)
{
    const float* xyz    = (const float*)d_in[0];
    const float* points = (const float*)d_in[1];
    const float* w0  = (const float*)d_in[2];
    const float* b0  = (const float*)d_in[3];
    const float* g0  = (const float*)d_in[4];
    const float* be0 = (const float*)d_in[5];
    const float* m0  = (const float*)d_in[6];
    const float* v0  = (const float*)d_in[7];
    const float* w1  = (const float*)d_in[8];
    const float* b1  = (const float*)d_in[9];
    const float* g1  = (const float*)d_in[10];
    const float* be1 = (const float*)d_in[11];
    const float* m1  = (const float*)d_in[12];
    const float* v1  = (const float*)d_in[13];
    const float* w2  = (const float*)d_in[14];
    const float* b2  = (const float*)d_in[15];
    const float* g2  = (const float*)d_in[16];
    const float* be2 = (const float*)d_in[17];
    const float* m2  = (const float*)d_in[18];
    const float* v2  = (const float*)d_in[19];

    float* out0 = (float*)d_out;                       // (16,3,1024)
    float* out1 = out0 + NBATCH * 3 * NPOINT;          // (16,128,1024)

    int*   ball = (int*)d_ws;                          // 16*1024*32 ints = 2 MB
    float* wp   = (float*)((char*)d_ws + (size_t)NBATCH*NPOINT*NSAMPLE*sizeof(int));

    hipLaunchKernelGGL(setup_kernel, dim3(1), dim3(256), 0, stream,
                       w0,b0,g0,be0,m0,v0, w1,b1,g1,be1,m1,v1, b2,g2,be2,m2,v2, wp);
    hipLaunchKernelGGL(fps_kernel,  dim3(NBATCH), dim3(1024), 0, stream, xyz, out0);
    hipLaunchKernelGGL(ball_kernel, dim3(NBATCH*NPOINT/4), dim3(256), 0, stream,
                       xyz, out0, ball);
    hipLaunchKernelGGL(mlp_kernel,  dim3(NBATCH*NPOINT*NSAMPLE/256), dim3(256), 0, stream,
                       xyz, points, out0, ball, wp, w2, out1);
}

// Round 7
// 1212.498 us; speedup vs baseline: 1.1514x; 1.1514x over previous
//
#include <hip/hip_runtime.h>
#include <hip/hip_bf16.h>

#define NPTS    4096
#define NBATCH  16
#define NPOINT  1024
#define NSAMPLE 32

// ---------------- DPP helpers (wave reductions without LDS round-trips) ---
#define ROW_SHR1  0x111
#define ROW_SHR2  0x112
#define ROW_SHR4  0x114
#define ROW_SHR8  0x118
#define ROW_BC15  0x142
#define ROW_BC31  0x143

template<int CTRL>
__device__ __forceinline__ unsigned dpp_mov(unsigned v) {
    // bound_ctrl=true: invalid source lanes produce 0 (safe: keys/vals >= 0)
    return (unsigned)__builtin_amdgcn_update_dpp(0, (int)v, CTRL, 0xF, 0xF, true);
}
template<int CTRL>
__device__ __forceinline__ unsigned long long dpp_max64(unsigned long long k) {
    unsigned lo = dpp_mov<CTRL>((unsigned)(k & 0xFFFFFFFFull));
    unsigned hi = dpp_mov<CTRL>((unsigned)(k >> 32));
    unsigned long long t = ((unsigned long long)hi << 32) | (unsigned long long)lo;
    return (t > k) ? t : k;
}
template<int CTRL>
__device__ __forceinline__ float dpp_maxf(float v) {
    unsigned t = dpp_mov<CTRL>(__float_as_uint(v));
    return fmaxf(v, __uint_as_float(t));
}

// ---------------- K1: farthest point sampling --------------------------------
// R2-R6 lesson: the compiler NEVER gives per-thread point arrays arch-VGPR
// residency (AGPR shuttling; cyc/iter tracked VGPR_Count 88/56/32/20 ->
// 1404/1577/1773/2100 across shapes & launch_bounds). Fix is structural:
// points live in LDS PLANES (read down the otherwise-idle LDS pipe, overlaps
// VALU), registers hold only dist[8]+temps (~30 regs -- nothing to shuttle).
//   XY[p] float2 + Z[p] float, storage index == logical point index.
//   Thread t, step j reads plane index j*512+t: consecutive lanes ->
//   consecutive float2/float = 2-way bank aliasing (free, m136).
// Strided ownership breaks lane-order tie-breaks -> u64 key reduce
// (dist_bits<<32)|~idx (exact, proven in R1): u64-max == (max dist, min idx).
// Per-wave: 6-step DPP; lane 63 ds_write_b64's its key to slot[w].
// Cross-wave: ds_read_b64 slot[lane&7] + 3-step DPP (lane 7 = max of 8) +
// 1 readlane -> winner idx; centroid via 2 uniform LDS reads. Outputs staged
// in LDS planes, one coalesced dump at the end; no global ops in-loop.
// Distances exact f32 (no fma), same assoc as np: (dx*dx+dy*dy)+dz*dz.
__global__ __launch_bounds__(512, 1) void fps_kernel(
    const float* __restrict__ xyz, float* __restrict__ newxyz)
{
    const int b    = blockIdx.x;
    const int tid  = threadIdx.x;
    const int lane = tid & 63;
    const int w    = tid >> 6;                       // 8 waves, 2/SIMD
    const float* xb = xyz + (size_t)b * 3 * NPTS;

    __shared__ float2 XY[NPTS];                      // 32 KiB
    __shared__ float  Zp[NPTS];                      // 16 KiB
    __shared__ float  NX[NPOINT], NY[NPOINT], NZ[NPOINT];  // 12 KiB
    __shared__ unsigned long long slots[2][8];       // 128 B

    // stage points: contiguous float4 global reads, plane writes
    #pragma unroll
    for (int q = 0; q < 2; ++q) {
        const int n4 = tid * 8 + q * 4;
        float4 xs = *(const float4*)(xb + n4);
        float4 ys = *(const float4*)(xb + NPTS + n4);
        float4 zs = *(const float4*)(xb + 2*NPTS + n4);
        XY[n4+0] = make_float2(xs.x, ys.x);  Zp[n4+0] = zs.x;
        XY[n4+1] = make_float2(xs.y, ys.y);  Zp[n4+1] = zs.y;
        XY[n4+2] = make_float2(xs.z, ys.z);  Zp[n4+2] = zs.z;
        XY[n4+3] = make_float2(xs.w, ys.w);  Zp[n4+3] = zs.w;
    }

    float dist[8];
    #pragma unroll
    for (int j = 0; j < 8; ++j) dist[j] = 1e10f;

    // first centroid = point 0 (uniform address -> scalar loads)
    float cx = xb[0], cy = xb[NPTS], cz = xb[2*NPTS];
    if (tid == 0) { NX[0] = cx; NY[0] = cy; NZ[0] = cz; }
    __syncthreads();

    for (int i = 1; i < NPOINT; ++i) {
        float bv = -1.0f; int bj = 0;
        #pragma unroll
        for (int j = 0; j < 8; ++j) {
            float2 xy = XY[j*512 + tid];
            float  zz = Zp[j*512 + tid];
            float dx = xy.x - cx;
            float dy = xy.y - cy;
            float dz = zz   - cz;
            // exact f32, no contraction, same assoc as np: (dx*dx+dy*dy)+dz*dz
            float d = __fadd_rn(__fadd_rn(__fmul_rn(dx,dx), __fmul_rn(dy,dy)),
                                __fmul_rn(dz,dz));
            float nd = fminf(dist[j], d);
            dist[j] = nd;
            bool t = nd > bv;                        // strict > : first max wins
            bv = t ? nd : bv;
            bj = t ? j  : bj;                        // j is an inline const
        }
        const unsigned idx = (unsigned)((bj << 9) + tid);
        unsigned long long key =
            ((unsigned long long)__float_as_uint(bv) << 32) |
            (unsigned long long)(unsigned)(~idx);
        key = dpp_max64<ROW_SHR1>(key);
        key = dpp_max64<ROW_SHR2>(key);
        key = dpp_max64<ROW_SHR4>(key);
        key = dpp_max64<ROW_SHR8>(key);
        key = dpp_max64<ROW_BC15>(key);
        key = dpp_max64<ROW_BC31>(key);              // lane 63 = wave max
        if (lane == 63) slots[i & 1][w] = key;       // direct ds_write_b64
        __syncthreads();

        unsigned long long kk = slots[i & 1][lane & 7];
        kk = dpp_max64<ROW_SHR1>(kk);
        kk = dpp_max64<ROW_SHR2>(kk);
        kk = dpp_max64<ROW_SHR4>(kk);                // lane 7 = max of 8 slots
        unsigned flo = (unsigned)__builtin_amdgcn_readlane(
            (int)(unsigned)(kk & 0xFFFFFFFFull), 7);
        const int f = (int)(~flo) & (NPTS - 1);      // winner index (uniform)

        float2 cxy = XY[f];                          // uniform broadcast reads
        float  czf = Zp[f];
        cx = cxy.x; cy = cxy.y; cz = czf;
        if (tid == 0) { NX[i] = cx; NY[i] = cy; NZ[i] = cz; }
    }

    __syncthreads();
    for (int t = tid; t < NPOINT; t += 512) {
        newxyz[b*3*NPOINT + t]            = NX[t];
        newxyz[b*3*NPOINT + NPOINT + t]   = NY[t];
        newxyz[b*3*NPOINT + 2*NPOINT + t] = NZ[t];
    }
}

// ---------------- K2: query_ball_point ---------------------------------------
// One wave per centroid: ordered scan of all 4096 points; ballot + prefix
// popcount emits the first 32 in-radius indices in ascending order; pad with
// the first found index. Exact f32 distances (no fma).
__global__ __launch_bounds__(256) void ball_kernel(
    const float* __restrict__ xyz, const float* __restrict__ newxyz,
    int* __restrict__ ball_idx)
{
    const int gid  = blockIdx.x * 256 + threadIdx.x;
    const int wid  = gid >> 6;                 // 0 .. 16383
    const int lane = threadIdx.x & 63;
    const int b    = wid >> 10;
    const int m    = wid & (NPOINT - 1);
    const float r2 = (float)(0.2 * 0.2);

    const float* xb = xyz + (size_t)b * 3 * NPTS;
    const float cx = newxyz[b*3*NPOINT + m];
    const float cy = newxyz[b*3*NPOINT + NPOINT + m];
    const float cz = newxyz[b*3*NPOINT + 2*NPOINT + m];
    int* out = ball_idx + (size_t)wid * NSAMPLE;

    int base = 0, first = 0;
    for (int c0 = 0; c0 < NPTS; c0 += 64) {
        const int n = c0 + lane;
        float dx = xb[n] - cx, dy = xb[NPTS+n] - cy, dz = xb[2*NPTS+n] - cz;
        float d = __fadd_rn(__fadd_rn(__fmul_rn(dx,dx), __fmul_rn(dy,dy)),
                            __fmul_rn(dz,dz));
        bool inb = (d <= r2);
        unsigned long long mask = __ballot(inb);
        if (base == 0 && mask != 0ull) first = c0 + (int)__builtin_ctzll(mask);
        int pos = base + __popcll(mask & ((1ull << lane) - 1ull));
        if (inb && pos < NSAMPLE) out[pos] = n;
        base += __popcll(mask);
        if (base >= NSAMPLE) break;
    }
    if (lane < NSAMPLE && lane >= base) out[lane] = first;  // pad with first index
}

// ---------------- K0: weight prep --------------------------------------------
// Transpose w0,w1 to k-major (so the MLP's per-k weight reads are contiguous
// wave-uniform scalar loads) and fold conv-bias + batchnorm into scale/shift.
__global__ __launch_bounds__(256) void setup_kernel(
    const float* __restrict__ w0, const float* __restrict__ b0,
    const float* __restrict__ g0, const float* __restrict__ be0,
    const float* __restrict__ m0, const float* __restrict__ v0,
    const float* __restrict__ w1, const float* __restrict__ b1,
    const float* __restrict__ g1, const float* __restrict__ be1,
    const float* __restrict__ m1, const float* __restrict__ v1,
    const float* __restrict__ b2, const float* __restrict__ g2,
    const float* __restrict__ be2, const float* __restrict__ m2,
    const float* __restrict__ v2, float* __restrict__ wp)
{
    const int t = threadIdx.x;
    for (int i = t; i < 64*67; i += 256) {
        int o = i / 67, k = i - o*67;
        wp[k*64 + o] = w0[i];                       // w0t [67][64]
    }
    for (int i = t; i < 64*64; i += 256) {
        int o = i >> 6, k = i & 63;
        wp[4288 + k*64 + o] = w1[i];                // w1t [64][64]
    }
    if (t < 64) {
        float s0 = g0[t] / sqrtf(v0[t] + 1e-5f);
        wp[8384 + t] = s0;
        wp[8448 + t] = (b0[t] - m0[t]) * s0 + be0[t];
        float s1 = g1[t] / sqrtf(v1[t] + 1e-5f);
        wp[8512 + t] = s1;
        wp[8576 + t] = (b1[t] - m1[t]) * s1 + be1[t];
    }
    if (t < 128) {
        float s2 = g2[t] / sqrtf(v2[t] + 1e-5f);
        wp[8640 + t] = s2;
        wp[8768 + t] = (b2[t] - m2[t]) * s2 + be2[t];
    }
}

// ---------------- K3: gather + 3-layer MLP + maxpool -------------------------
// One lane per (centroid, sample) column. 64 lanes = 2 centroids x 32 samples.
// All activations in VGPRs; weights via wave-uniform scalar loads; max over
// 32 samples with a 5-step DPP chain; lanes 31/63 store.
__global__ __launch_bounds__(256) void mlp_kernel(
    const float* __restrict__ xyz, const float* __restrict__ points,
    const float* __restrict__ newxyz, const int* __restrict__ ball_idx,
    const float* __restrict__ wp, const float* __restrict__ w2,
    float* __restrict__ out)
{
    const int col = blockIdx.x * 256 + threadIdx.x;   // 0 .. 524287
    const int m   = (col >> 5) & (NPOINT - 1);
    const int b   = col >> 15;
    const int p   = ball_idx[col];

    const float* xb = xyz + (size_t)b * 3 * NPTS;
    float in[67];
    in[0] = xb[p]          - newxyz[b*3*NPOINT + m];
    in[1] = xb[NPTS + p]   - newxyz[b*3*NPOINT + NPOINT + m];
    in[2] = xb[2*NPTS + p] - newxyz[b*3*NPOINT + 2*NPOINT + m];
    const float* pb = points + (size_t)b * 64 * NPTS;
    #pragma unroll
    for (int c = 0; c < 64; ++c) in[3 + c] = pb[c * NPTS + p];

    const float* w0t = wp;
    const float* w1t = wp + 4288;
    const float* sc0 = wp + 8384;
    const float* sh0 = wp + 8448;
    const float* sc1 = wp + 8512;
    const float* sh1 = wp + 8576;
    const float* sc2 = wp + 8640;
    const float* sh2 = wp + 8768;

    float h[64];
    #pragma unroll
    for (int o = 0; o < 64; ++o) h[o] = 0.0f;
    #pragma unroll
    for (int k = 0; k < 67; ++k) {
        const float x = in[k];
        #pragma unroll
        for (int o = 0; o < 64; ++o) h[o] = fmaf(w0t[k*64 + o], x, h[o]);
    }
    #pragma unroll
    for (int o = 0; o < 64; ++o)
        h[o] = fmaxf(fmaf(h[o], sc0[o], sh0[o]), 0.0f);

    float g[64];
    #pragma unroll
    for (int o = 0; o < 64; ++o) g[o] = 0.0f;
    #pragma unroll
    for (int k = 0; k < 64; ++k) {
        const float x = h[k];
        #pragma unroll
        for (int o = 0; o < 64; ++o) g[o] = fmaf(w1t[k*64 + o], x, g[o]);
    }
    #pragma unroll
    for (int o = 0; o < 64; ++o)
        g[o] = fmaxf(fmaf(g[o], sc1[o], sh1[o]), 0.0f);

    float* outb = out + (size_t)b * 128 * NPOINT + m;
    #pragma unroll 2
    for (int o = 0; o < 128; ++o) {
        float acc = 0.0f;
        const float* wr = w2 + o * 64;
        #pragma unroll
        for (int k = 0; k < 64; ++k) acc = fmaf(wr[k], g[k], acc);
        acc = fmaxf(fmaf(acc, sc2[o], sh2[o]), 0.0f);
        acc = dpp_maxf<ROW_SHR1>(acc);
        acc = dpp_maxf<ROW_SHR2>(acc);
        acc = dpp_maxf<ROW_SHR4>(acc);
        acc = dpp_maxf<ROW_SHR8>(acc);
        acc = dpp_maxf<ROW_BC15>(acc);            // lane31 = max(0..31), lane63 = max(32..63)
        if ((threadIdx.x & 31) == 31) outb[o * NPOINT] = acc;
    }
}

// ---------------- launch ------------------------------------------------------
extern "C" void kernel_launch(void* const* d_in, const int* in_sizes, int n_in,
                              void* d_out, int out_size, void* d_ws, size_t ws_size,
                              hipStream_t stream)
{
    const float* xyz    = (const float*)d_in[0];
    const float* points = (const float*)d_in[1];
    const float* w0  = (const float*)d_in[2];
    const float* b0  = (const float*)d_in[3];
    const float* g0  = (const float*)d_in[4];
    const float* be0 = (const float*)d_in[5];
    const float* m0  = (const float*)d_in[6];
    const float* v0  = (const float*)d_in[7];
    const float* w1  = (const float*)d_in[8];
    const float* b1  = (const float*)d_in[9];
    const float* g1  = (const float*)d_in[10];
    const float* be1 = (const float*)d_in[11];
    const float* m1  = (const float*)d_in[12];
    const float* v1  = (const float*)d_in[13];
    const float* w2  = (const float*)d_in[14];
    const float* b2  = (const float*)d_in[15];
    const float* g2  = (const float*)d_in[16];
    const float* be2 = (const float*)d_in[17];
    const float* m2  = (const float*)d_in[18];
    const float* v2  = (const float*)d_in[19];

    float* out0 = (float*)d_out;                       // (16,3,1024)
    float* out1 = out0 + NBATCH * 3 * NPOINT;          // (16,128,1024)

    int*   ball = (int*)d_ws;                          // 16*1024*32 ints = 2 MB
    float* wp   = (float*)((char*)d_ws + (size_t)NBATCH*NPOINT*NSAMPLE*sizeof(int));

    hipLaunchKernelGGL(setup_kernel, dim3(1), dim3(256), 0, stream,
                       w0,b0,g0,be0,m0,v0, w1,b1,g1,be1,m1,v1, b2,g2,be2,m2,v2, wp);
    hipLaunchKernelGGL(fps_kernel,  dim3(NBATCH), dim3(512), 0, stream, xyz, out0);
    hipLaunchKernelGGL(ball_kernel, dim3(NBATCH*NPOINT/4), dim3(256), 0, stream,
                       xyz, out0, ball);
    hipLaunchKernelGGL(mlp_kernel,  dim3(NBATCH*NPOINT*NSAMPLE/256), dim3(256), 0, stream,
                       xyz, points, out0, ball, wp, w2, out1);
}